// Round 9
// baseline (575.974 us; speedup 1.0000x reference)
//
#include <hip/hip_runtime.h>
#include <stdint.h>

typedef _Float16 f16;
typedef _Float16 half8_t __attribute__((ext_vector_type(8)));
typedef _Float16 half4_t __attribute__((ext_vector_type(4)));
typedef float floatx4 __attribute__((ext_vector_type(4)));

#define B_  64
#define LA_ 512
#define LB_ 512
#define H_  768

// XOR swizzle on 16B chunks within a 128B row (T2). Same involution on write
// (ds_write / pre-swizzled gload source) and ds_read (rule #21).
static __device__ __forceinline__ int swz(int row, int byteInRow) {
    return row * 128 + (byteInRow ^ ((row & 7) << 4));
}

// async global->LDS, 16B/lane. LDS dest wave-uniform base + lane*16 (m104);
// per-lane global address carries the inverse swizzle.
static __device__ __forceinline__ void gload16(const void* g, void* l) {
    __builtin_amdgcn_global_load_lds(
        (const __attribute__((address_space(1))) unsigned int*)g,
        (__attribute__((address_space(3))) unsigned int*)l,
        16, 0, 0);
}

// ---------------------------------------------------------------------------
// K-1: zero lrow/lcol (harness poisons ws with 0xAA; qk accumulates atomically)
// 256 KB contiguous: 16384 float4. grid 64 x 256.
// ---------------------------------------------------------------------------
__global__ __launch_bounds__(256) void zeroinit_kernel(float* __restrict__ p) {
    const int i = blockIdx.x * 256 + threadIdx.x;
    ((floatx4*)p)[i] = floatx4{0.f, 0.f, 0.f, 0.f};
}

// ---------------------------------------------------------------------------
// K0: conv_t — fp32 a,b -> fp16 TRANSPOSED [B][H][L] (aT,bT) only.
// (row-major fp16 copies eliminated; qk now reads fp32 directly.)
// grid (H/64, L/64, 2*B), block 256. Streaming -> no XCD swizzle.
// ---------------------------------------------------------------------------
__global__ __launch_bounds__(256) void conv_kernel(
    const float* __restrict__ A, const float* __restrict__ Bm,
    f16* __restrict__ aT, f16* __restrict__ bT)
{
    __shared__ f16 Ts[64][68];   // pad 68: transposed column reads spread banks

    const int t  = threadIdx.x;
    const int hb = blockIdx.x * 64, lb = blockIdx.y * 64;
    const int z  = blockIdx.z, b = z >> 1, which = z & 1;

    const float* src = which ? Bm : A;
    f16* dT = which ? bT : aT;

    const int r = t >> 2, cs = (t & 3) * 16;
    const float* s = src + (size_t)(b * 512 + lb + r) * H_ + hb + cs;

    #pragma unroll
    for (int q = 0; q < 4; ++q) {
        floatx4 v = ((const floatx4*)s)[q];
        #pragma unroll
        for (int e = 0; e < 4; ++e) Ts[r][cs + q * 4 + e] = (f16)v[e];
    }
    __syncthreads();

    const int h = t >> 2, ls = (t & 3) * 16;
    half8_t v0, v1;
    #pragma unroll
    for (int e = 0; e < 8; ++e) { v0[e] = Ts[ls + e][h]; v1[e] = Ts[ls + 8 + e][h]; }
    f16* dTrow = dT + ((size_t)b * H_ + hb + h) * 512 + lb + ls;
    *(half8_t*)dTrow = v0;
    *(half8_t*)(dTrow + 8) = v1;
}

// ---------------------------------------------------------------------------
// K1: qk_f32 — S = a.b^T * temp from FP32 inputs (reg-stage + cvt + swizzled
// ds_write, single-barrier dbuf), P = exp(S) fp16 row-major + transposed,
// PLUS fused row/col sums (butterfly shfl -> LDS -> global atomicAdd).
// flat grid 1024, bijective XCD swizzle.
// ---------------------------------------------------------------------------
__global__ __launch_bounds__(256) void qk_f32_kernel(
    const float* __restrict__ Ag, const float* __restrict__ Bg,
    const int* __restrict__ maskA, const int* __restrict__ maskB,
    const float* __restrict__ temp_p,
    f16* __restrict__ P, f16* __restrict__ PT,
    float* __restrict__ lrow, float* __restrict__ lcol)
{
    __shared__ f16 As[2][128 * 64];
    __shared__ f16 Bs[2][128 * 64];
    __shared__ int mA[128];
    __shared__ int mB[128];
    __shared__ float rsum[128];
    __shared__ float csum[128];

    const int t    = threadIdx.x;
    const int lane = t & 63;
    const int w    = t >> 6;
    const int wm   = w >> 1, wn = w & 1;

    // XCD swizzle: XCD k owns contiguous ids [k*128,(k+1)*128) = 8 b-slices.
    int id = (int)blockIdx.x;
    id = (id & 7) * 128 + (id >> 3);
    const int jb = (id & 3) * 128;
    const int ib = ((id >> 2) & 3) * 128;
    const int b  = id >> 4;

    if (t < 128) { mA[t] = maskA[b * LA_ + ib + t]; rsum[t] = 0.f; csum[t] = 0.f; }
    else         { mB[t - 128] = maskB[b * LB_ + jb + (t - 128)]; }

    floatx4 acc[4][4] = {};

    const int row  = t >> 1;
    const int half = t & 1;
    const float* srcA = Ag + (size_t)(b * LA_ + ib + row) * H_ + half * 32;
    const float* srcB = Bg + (size_t)(b * LB_ + jb + row) * H_ + half * 32;

    floatx4 a4[8], b4[8];
    #define QK_LOAD(kt)                                                   \
        {                                                                 \
            const floatx4* pa = (const floatx4*)(srcA + (kt) * 64);       \
            const floatx4* pb = (const floatx4*)(srcB + (kt) * 64);       \
            _Pragma("unroll")                                             \
            for (int q = 0; q < 8; ++q) { a4[q] = pa[q]; b4[q] = pb[q]; } \
        }
    #define QK_DSWRITE(bufi)                                              \
        _Pragma("unroll")                                                 \
        for (int q = 0; q < 4; ++q) {                                     \
            half8_t ha, hb;                                               \
            _Pragma("unroll")                                             \
            for (int e = 0; e < 8; ++e) {                                 \
                ha[e] = (f16)(a4[2 * q + (e >> 2)][e & 3]);               \
                hb[e] = (f16)(b4[2 * q + (e >> 2)][e & 3]);               \
            }                                                             \
            const int off = swz(row, (half * 4 + q) * 16);                \
            *(half8_t*)((char*)As[bufi] + off) = ha;                      \
            *(half8_t*)((char*)Bs[bufi] + off) = hb;                      \
        }

    QK_LOAD(0);
    QK_DSWRITE(0);
    int cur = 0;

    for (int kt = 0; kt < H_ / 64; ++kt) {
        if (kt + 1 < H_ / 64) { QK_LOAD(kt + 1); }   // in flight under MFMA
        __syncthreads();                              // buf[cur] ready
        char* AsB = (char*)As[cur];
        char* BsB = (char*)Bs[cur];
        #pragma unroll
        for (int ks = 0; ks < 2; ++ks) {
            half8_t af[4], bf[4];
            #pragma unroll
            for (int m = 0; m < 4; ++m) {
                const int r = wm * 64 + m * 16 + (lane & 15);
                af[m] = *(half8_t*)(AsB + swz(r, ks * 64 + ((lane >> 4) << 4)));
            }
            #pragma unroll
            for (int n = 0; n < 4; ++n) {
                const int r = wn * 64 + n * 16 + (lane & 15);
                bf[n] = *(half8_t*)(BsB + swz(r, ks * 64 + ((lane >> 4) << 4)));
            }
            #pragma unroll
            for (int m = 0; m < 4; ++m)
                #pragma unroll
                for (int n = 0; n < 4; ++n)
                    acc[m][n] = __builtin_amdgcn_mfma_f32_16x16x32_f16(
                        af[m], bf[n], acc[m][n], 0, 0, 0);
        }
        if (kt + 1 < H_ / 64) { QK_DSWRITE(cur ^ 1); }  // safe: other buffer
        cur ^= 1;
    }
    #undef QK_LOAD
    #undef QK_DSWRITE

    // epilogue: P = mask ? exp(S*temp) : 0 ; store P + PT ; accumulate sums
    const float temp = *temp_p;
    float rs[4][4];              // [m][r] partial row sums (this thread's 4 j)
    float cspart[4];             // [n]    partial col sums (this thread's 16 i)
    #pragma unroll
    for (int m = 0; m < 4; ++m)
        #pragma unroll
        for (int r = 0; r < 4; ++r) rs[m][r] = 0.f;
    #pragma unroll
    for (int n = 0; n < 4; ++n) cspart[n] = 0.f;

    #pragma unroll
    for (int m = 0; m < 4; ++m) {
        const int iloc0 = wm * 64 + m * 16 + ((lane >> 4) << 2);
        #pragma unroll
        for (int n = 0; n < 4; ++n) {
            const int jloc = wn * 64 + n * 16 + (lane & 15);
            const int vb = mB[jloc];
            half4_t hv;
            #pragma unroll
            for (int r = 0; r < 4; ++r) {
                const int iloc = iloc0 + r;
                const float s = acc[m][n][r] * temp;
                const float p = (mA[iloc] && vb) ? __expf(s) : 0.0f;
                hv[r] = (f16)p;
                const float pf = (float)hv[r];   // sum the rounded value
                rs[m][r] += pf;
                cspart[n] += pf;
                P[(size_t)(b * LA_ + ib + iloc) * LB_ + jb + jloc] = hv[r];
            }
            *(half4_t*)(PT + (size_t)(b * LB_ + jb + jloc) * LA_ + ib + iloc0) = hv;
        }
    }

    // row sums: reduce across the 16 j-lanes of each quarter-wave
    #pragma unroll
    for (int m = 0; m < 4; ++m) {
        const int iloc0 = wm * 64 + m * 16 + ((lane >> 4) << 2);
        #pragma unroll
        for (int r = 0; r < 4; ++r) {
            float v = rs[m][r];
            v += __shfl_xor(v, 1); v += __shfl_xor(v, 2);
            v += __shfl_xor(v, 4); v += __shfl_xor(v, 8);
            if ((lane & 15) == 0) atomicAdd(&rsum[iloc0 + r], v);
        }
    }
    // col sums: reduce across the 4 quarter-wave groups (i-direction)
    #pragma unroll
    for (int n = 0; n < 4; ++n) {
        float v = cspart[n];
        v += __shfl_xor(v, 16); v += __shfl_xor(v, 32);
        if (lane < 16) atomicAdd(&csum[wn * 64 + n * 16 + lane], v);
    }
    __syncthreads();
    if (t < 128) atomicAdd(&lrow[b * 512 + ib + t], rsum[t]);
    else         atomicAdd(&lcol[b * 512 + jb + (t - 128)], csum[t - 128]);
}

// ---------------------------------------------------------------------------
// K2: pv16 — unchanged from round 6 (passing, profiled): feature =
// diag(1/l) * Pmat . V, fp16 x fp16, gload_lds dbuf, XCD swizzle (nwg=3072).
// ---------------------------------------------------------------------------
__global__ __launch_bounds__(256) void pv16_kernel(
    const f16* __restrict__ P, const f16* __restrict__ PT,
    const f16* __restrict__ aT, const f16* __restrict__ bT,
    const float* __restrict__ lrow, const float* __restrict__ lcol,
    float* __restrict__ out)
{
    __shared__ f16 As[2][128 * 64];
    __shared__ f16 Vs[2][128 * 64];
    __shared__ float Sc[128];

    const int t    = threadIdx.x;
    const int lane = t & 63;
    const int w    = t >> 6;
    const int wm   = w >> 1, wn = w & 1;

    int id = (int)blockIdx.x;
    id = (id & 7) * 384 + (id >> 3);
    const int hb = (id % 6) * 128;
    const int rem = id / 6;
    const int ib = (rem & 3) * 128;
    const int z  = rem >> 2;
    const int dir = z >> 6;
    const int b   = z & 63;

    const f16* Ab = (dir ? PT : P) + (size_t)(b * 512 + ib) * 512;
    const f16* Vb = (dir ? aT : bT) + ((size_t)b * H_ + hb) * 512;
    const float* lsrc = dir ? lcol : lrow;
    float* o = out + (size_t)dir * ((size_t)B_ * LA_ * H_)
                   + (size_t)(b * 512 + ib) * H_ + hb;

    if (t < 128) {
        const float l = lsrc[b * 512 + ib + t];
        Sc[t] = (l > 0.f) ? 1.0f / l : 0.0f;
    }

    floatx4 acc[4][4] = {};

    int srow[4], sbyt[4];
    #pragma unroll
    for (int q = 0; q < 4; ++q) {
        const int o2 = (q * 4 + w) * 1024 + lane * 16;
        srow[q] = o2 >> 7;
        sbyt[q] = (o2 & 127) ^ ((srow[q] & 7) << 4);
    }

    #define PV_STAGE(bufi, kt)                                            \
        _Pragma("unroll")                                                 \
        for (int q = 0; q < 4; ++q) {                                     \
            const int wc = q * 4 + w;                                     \
            const size_t go = (size_t)srow[q] * 512 + (kt) * 64 + (sbyt[q] >> 1); \
            gload16(Ab + go, (char*)As[bufi] + wc * 1024);                \
            gload16(Vb + go, (char*)Vs[bufi] + wc * 1024);                \
        }

    PV_STAGE(0, 0);
    int cur = 0;

    for (int kt = 0; kt < 512 / 64; ++kt) {
        __syncthreads();
        if (kt + 1 < 512 / 64) { PV_STAGE(cur ^ 1, kt + 1); }

        char* AsB = (char*)As[cur];
        char* VsB = (char*)Vs[cur];
        #pragma unroll
        for (int ks = 0; ks < 2; ++ks) {
            half8_t af[4], vf[4];
            #pragma unroll
            for (int m = 0; m < 4; ++m) {
                const int r = wm * 64 + m * 16 + (lane & 15);
                af[m] = *(half8_t*)(AsB + swz(r, ks * 64 + ((lane >> 4) << 4)));
            }
            #pragma unroll
            for (int n = 0; n < 4; ++n) {
                const int r = wn * 64 + n * 16 + (lane & 15);
                vf[n] = *(half8_t*)(VsB + swz(r, ks * 64 + ((lane >> 4) << 4)));
            }
            #pragma unroll
            for (int m = 0; m < 4; ++m)
                #pragma unroll
                for (int n = 0; n < 4; ++n)
                    acc[m][n] = __builtin_amdgcn_mfma_f32_16x16x32_f16(
                        af[m], vf[n], acc[m][n], 0, 0, 0);
        }
        cur ^= 1;
    }
    #undef PV_STAGE

    #pragma unroll
    for (int m = 0; m < 4; ++m) {
        const int iloc0 = wm * 64 + m * 16 + ((lane >> 4) << 2);
        #pragma unroll
        for (int n = 0; n < 4; ++n) {
            const int hloc = wn * 64 + n * 16 + (lane & 15);
            #pragma unroll
            for (int r = 0; r < 4; ++r) {
                const int iloc = iloc0 + r;
                o[(size_t)iloc * H_ + hloc] = acc[m][n][r] * Sc[iloc];
            }
        }
    }
}

// ---------------------------------------------------------------------------
extern "C" void kernel_launch(void* const* d_in, const int* in_sizes, int n_in,
                              void* d_out, int out_size, void* d_ws, size_t ws_size,
                              hipStream_t stream)
{
    const float* a    = (const float*)d_in[0];
    const float* b    = (const float*)d_in[1];
    const int*   ma   = (const int*)d_in[2];
    const int*   mb   = (const int*)d_in[3];
    const float* temp = (const float*)d_in[4];
    float*       out  = (float*)d_out;
    char*        ws   = (char*)d_ws;

    // ws layout: aT 50331648 | bT 50331648 | P 33554432 | PT 33554432 |
    //            lrow 131072 | lcol 131072
    const size_t NEED = 168034304;
    if (ws_size < NEED) return;

    f16*   aT   = (f16*)(ws);
    f16*   bT   = (f16*)(ws + 50331648);
    f16*   P    = (f16*)(ws + 100663296);
    f16*   PT   = (f16*)(ws + 134217728);
    float* lrow = (float*)(ws + 167772160);
    float* lcol = (float*)(ws + 167903232);

    zeroinit_kernel<<<dim3(64, 1, 1), 256, 0, stream>>>(lrow);  // lrow+lcol 256KB
    conv_kernel<<<dim3(H_ / 64, 512 / 64, 2 * B_), 256, 0, stream>>>(
        a, b, aT, bT);
    qk_f32_kernel<<<dim3(1024, 1, 1), 256, 0, stream>>>(
        a, b, ma, mb, temp, P, PT, lrow, lcol);
    pv16_kernel<<<dim3(3072, 1, 1), 256, 0, stream>>>(
        P, PT, aT, bT, lrow, lcol, out);
}